// Round 10
// baseline (131.116 us; speedup 1.0000x reference)
//
#include <hip/hip_runtime.h>
#include <hip/hip_bf16.h>

// Problem constants (from reference setup_inputs)
#define B_   16
#define C_   64
#define HW_  65536   // 256*256

typedef float    f2_t __attribute__((ext_vector_type(2)));
typedef float    f4_t __attribute__((ext_vector_type(4)));
typedef _Float16 h2_t __attribute__((ext_vector_type(2)));
typedef _Float16 h4_t __attribute__((ext_vector_type(4)));

// fast branch-free tanh: 1 - 2/(e^2z + 1), clamped
__device__ __forceinline__ float fast_tanh(float z) {
    z = fminf(fmaxf(z, -15.f), 15.f);
    float e = __expf(2.f * z);
    return 1.f - 2.f * __builtin_amdgcn_rcpf(e + 1.f);
}

// ---------------------------------------------------------------------------
// Kernel 1 (compress path): x_node[b,c] = mean of x[b,c,:,:]  AND
// xh = fp16(x). x is read with NON-TEMPORAL loads (keep L3 clean); xh is
// written with regular allocating stores (128 MiB -> stays hot in 256 MiB L3).
// grid = B*C = 1024 blocks, 256 threads.
// ---------------------------------------------------------------------------
__global__ __launch_bounds__(256) void k_reduce_compress(
    const float* __restrict__ x, float* __restrict__ x_node,
    h4_t* __restrict__ xh) {
    int bc  = blockIdx.x;                    // b*64 + c
    int tid = threadIdx.x;
    const f4_t* p4 = (const f4_t*)(x + (size_t)bc * HW_);
    h4_t* oh = xh + (size_t)bc * (HW_ / 4);

    float s = 0.f;
#pragma unroll
    for (int i = 0; i < 64; ++i) {
        f4_t v = __builtin_nontemporal_load(p4 + tid + 256 * i);
        s += (v.x + v.y) + (v.z + v.w);
        h4_t h;
        h.x = (_Float16)v.x; h.y = (_Float16)v.y;
        h.z = (_Float16)v.z; h.w = (_Float16)v.w;
        oh[tid + 256 * i] = h;
    }
#pragma unroll
    for (int off = 32; off; off >>= 1) s += __shfl_down(s, off, 64);

    __shared__ float ls[4];
    int wid = tid >> 6, lane = tid & 63;
    if (lane == 0) ls[wid] = s;
    __syncthreads();
    if (tid == 0) {
        float t = (ls[0] + ls[1]) + (ls[2] + ls[3]);
        x_node[bc] = t * (1.0f / (float)HW_);
    }
}

// ---------------------------------------------------------------------------
// Kernel 2 (compress path): per-block GCN math, then register pixel pass
// reading fp16 xh (L3-hot), writing fp32 out with nt stores.
// grid = B * (HW/512) = 2048 blocks; 128 blocks per batch, reversed chunks.
// ---------------------------------------------------------------------------
__global__ __launch_bounds__(256) void k_fused_h(
    const _Float16* __restrict__ xh, const float* __restrict__ x_node,
    const float* __restrict__ theta_w, const float* __restrict__ theta_b,
    const float* __restrict__ g1_w,    const float* __restrict__ g1_b,
    const float* __restrict__ g2_w,    const float* __restrict__ g2_b,
    const float* __restrict__ phi_w,   const float* __restrict__ phi_b,
    float* __restrict__ out) {
    __shared__ float xn[C_], z1[C_], wsh[C_], pw[C_], pb[C_];
    __shared__ float hp[4][C_];
    __shared__ float bias_s;

    int t = threadIdx.x;
    int b = blockIdx.x >> 7;                 // 128 blocks per batch
    int chunk = 127 - (blockIdx.x & 127);    // reversed pixel order
    int pix = (chunk * 256 + t) * 2;

    // ---- per-block tiny GCN math (redundant, deterministic) ----
    int n = t & 63, q = t >> 6;
    if (t < C_) { xn[t] = x_node[b * C_ + t]; pw[t] = phi_w[t]; pb[t] = phi_b[t]; }
    __syncthreads();
    float hpart = 0.f;
#pragma unroll
    for (int i = 0; i < 16; ++i) {
        int c = q * 16 + i;
        hpart += xn[c] * g1_w[n * C_ + c];
    }
    hp[q][n] = hpart;
    __syncthreads();
    if (t < C_) {
        float h = g1_b[t] + (hp[0][t] + hp[1][t]) + (hp[2][t] + hp[3][t]);
        z1[t] = h * g2_w[0] + g2_b[0];
    }
    __syncthreads();
    float wpart = 0.f;
#pragma unroll
    for (int i = 0; i < 16; ++i) {
        int nn = q * 16 + i;
        wpart += z1[nn] * theta_w[nn * C_ + n];
    }
    hp[q][n] = wpart;                        // reuse hp
    if (t == 0) {
        float bb = 0.f;
#pragma unroll
        for (int nn = 0; nn < C_; ++nn) bb += z1[nn] * theta_b[nn];
        bias_s = bb;
    }
    __syncthreads();
    if (t < C_) wsh[t] = (hp[0][t] + hp[1][t]) + (hp[2][t] + hp[3][t]);
    __syncthreads();

    // ---- register pixel pass on fp16 data ----
    const h2_t* xb = (const h2_t*)(xh + (size_t)b * C_ * HW_ + pix);

    h2_t xs[C_];                             // 64 VGPRs
    float y0 = bias_s;
    float y1 = y0;
#pragma unroll
    for (int c = 0; c < C_; ++c) {
        h2_t v = xb[c * (HW_ / 2)];
        xs[c] = v;
        float w = wsh[c];
        y0 += w * (float)v.x;
        y1 += w * (float)v.y;
    }

    float* ob = out + (size_t)b * C_ * HW_ + pix;
#pragma unroll
    for (int c = 0; c < C_; ++c) {
        float a = pw[c], d = pb[c];
        f2_t r;
        r.x = fast_tanh(y0 * a + d + (float)xs[c].x);
        r.y = fast_tanh(y1 * a + d + (float)xs[c].y);
        __builtin_nontemporal_store(r, (f2_t*)(ob + (size_t)c * HW_));
    }
}

// ===========================================================================
// Fallback path (round-9 proven): fp32 re-read, used only if ws too small.
// ===========================================================================
__global__ __launch_bounds__(256) void k_reduce_mean(
    const float* __restrict__ x, float* __restrict__ x_node) {
    int bc  = blockIdx.x;
    int tid = threadIdx.x;
    const float4* p4 = (const float4*)(x + (size_t)bc * HW_);
    float s = 0.f;
#pragma unroll
    for (int i = 0; i < 64; ++i) {
        float4 v = p4[tid + 256 * i];
        s += (v.x + v.y) + (v.z + v.w);
    }
#pragma unroll
    for (int off = 32; off; off >>= 1) s += __shfl_down(s, off, 64);
    __shared__ float ls[4];
    int wid = tid >> 6, lane = tid & 63;
    if (lane == 0) ls[wid] = s;
    __syncthreads();
    if (tid == 0)
        x_node[bc] = ((ls[0] + ls[1]) + (ls[2] + ls[3])) * (1.0f / (float)HW_);
}

__global__ __launch_bounds__(256) void k_fused_reg(
    const float* __restrict__ x, const float* __restrict__ x_node,
    const float* __restrict__ theta_w, const float* __restrict__ theta_b,
    const float* __restrict__ g1_w,    const float* __restrict__ g1_b,
    const float* __restrict__ g2_w,    const float* __restrict__ g2_b,
    const float* __restrict__ phi_w,   const float* __restrict__ phi_b,
    float* __restrict__ out) {
    __shared__ float xn[C_], z1[C_], wsh[C_], pw[C_], pb[C_];
    __shared__ float hp[4][C_];
    __shared__ float bias_s;

    int t = threadIdx.x;
    int b = blockIdx.x >> 7;
    int chunk = 127 - (blockIdx.x & 127);
    int pix = (chunk * 256 + t) * 2;

    int n = t & 63, q = t >> 6;
    if (t < C_) { xn[t] = x_node[b * C_ + t]; pw[t] = phi_w[t]; pb[t] = phi_b[t]; }
    __syncthreads();
    float hpart = 0.f;
#pragma unroll
    for (int i = 0; i < 16; ++i) {
        int c = q * 16 + i;
        hpart += xn[c] * g1_w[n * C_ + c];
    }
    hp[q][n] = hpart;
    __syncthreads();
    if (t < C_) {
        float h = g1_b[t] + (hp[0][t] + hp[1][t]) + (hp[2][t] + hp[3][t]);
        z1[t] = h * g2_w[0] + g2_b[0];
    }
    __syncthreads();
    float wpart = 0.f;
#pragma unroll
    for (int i = 0; i < 16; ++i) {
        int nn = q * 16 + i;
        wpart += z1[nn] * theta_w[nn * C_ + n];
    }
    hp[q][n] = wpart;
    if (t == 0) {
        float bb = 0.f;
#pragma unroll
        for (int nn = 0; nn < C_; ++nn) bb += z1[nn] * theta_b[nn];
        bias_s = bb;
    }
    __syncthreads();
    if (t < C_) wsh[t] = (hp[0][t] + hp[1][t]) + (hp[2][t] + hp[3][t]);
    __syncthreads();

    const float* xb = x + (size_t)b * C_ * HW_ + pix;
    f2_t xs[C_];
    float y0 = bias_s;
    float y1 = y0;
#pragma unroll
    for (int c = 0; c < C_; ++c) {
        f2_t v = *(const f2_t*)(xb + (size_t)c * HW_);
        xs[c] = v;
        float w = wsh[c];
        y0 += w * v.x;
        y1 += w * v.y;
    }
    float* ob = out + (size_t)b * C_ * HW_ + pix;
#pragma unroll
    for (int c = 0; c < C_; ++c) {
        float a = pw[c], d = pb[c];
        f2_t r;
        r.x = fast_tanh(y0 * a + d + xs[c].x);
        r.y = fast_tanh(y1 * a + d + xs[c].y);
        __builtin_nontemporal_store(r, (f2_t*)(ob + (size_t)c * HW_));
    }
}

// ---------------------------------------------------------------------------
extern "C" void kernel_launch(void* const* d_in, const int* in_sizes, int n_in,
                              void* d_out, int out_size, void* d_ws, size_t ws_size,
                              hipStream_t stream) {
    const float* x       = (const float*)d_in[0];
    const float* theta_w = (const float*)d_in[1];
    const float* theta_b = (const float*)d_in[2];
    const float* g1_w    = (const float*)d_in[3];
    const float* g1_b    = (const float*)d_in[4];
    const float* g2_w    = (const float*)d_in[5];
    const float* g2_b    = (const float*)d_in[6];
    const float* phi_w   = (const float*)d_in[7];
    const float* phi_b   = (const float*)d_in[8];
    float* out = (float*)d_out;

    float* x_node = (float*)d_ws;            // B*C floats (4 KiB)
    const size_t xh_off   = 4096;
    const size_t xh_bytes = (size_t)B_ * C_ * HW_ * sizeof(_Float16); // 128 MiB

    if (ws_size >= xh_off + xh_bytes) {
        _Float16* xh = (_Float16*)((char*)d_ws + xh_off);
        k_reduce_compress<<<B_ * C_, 256, 0, stream>>>(x, x_node, (h4_t*)xh);
        k_fused_h<<<B_ * (HW_ / 512), 256, 0, stream>>>(
            xh, x_node, theta_w, theta_b, g1_w, g1_b, g2_w, g2_b,
            phi_w, phi_b, out);
    } else {
        k_reduce_mean<<<B_ * C_, 256, 0, stream>>>(x, x_node);
        k_fused_reg<<<B_ * (HW_ / 512), 256, 0, stream>>>(
            x, x_node, theta_w, theta_b, g1_w, g1_b, g2_w, g2_b,
            phi_w, phi_b, out);
    }
}